// Round 13
// baseline (305.407 us; speedup 1.0000x reference)
//
#include <hip/hip_runtime.h>

typedef unsigned short ushort_t;
typedef unsigned int uint_t;
typedef __attribute__((ext_vector_type(8))) short short8;
typedef __attribute__((ext_vector_type(8))) _Float16 half8;
typedef __attribute__((ext_vector_type(4))) _Float16 half4;
typedef __attribute__((ext_vector_type(4))) float float4v;

#define MFMA_BF16(a, b, c) __builtin_amdgcn_mfma_f32_16x16x32_bf16((a), (b), (c), 0, 0, 0)
#define MFMA_F16(a, b, c) __builtin_amdgcn_mfma_f32_16x16x32_f16((a), (b), (c), 0, 0, 0)

#define NQ 8192
#define DIM 256
#define DV 512

// round-to-nearest-even f32 -> bf16 (raw bits)
__device__ __forceinline__ ushort_t f2bf(float x) {
  union { float f; uint_t u; } v; v.f = x;
  return (ushort_t)((v.u + 0x7fffu + ((v.u >> 16) & 1u)) >> 16);
}
__device__ __forceinline__ float bf2f(ushort_t b) {
  union { uint_t u; float f; } v; v.u = ((uint_t)b) << 16;
  return v.f;
}

__device__ __forceinline__ half8 cvt8h(const float* p) {
  float4v a = *(const float4v*)p;
  float4v b = *(const float4v*)(p + 4);
  half8 r;
  r[0] = (_Float16)a[0]; r[1] = (_Float16)a[1];
  r[2] = (_Float16)a[2]; r[3] = (_Float16)a[3];
  r[4] = (_Float16)b[0]; r[5] = (_Float16)b[1];
  r[6] = (_Float16)b[2]; r[7] = (_Float16)b[3];
  return r;
}

__device__ __forceinline__ half8 as_h8(short8 s) {
  union { short8 s; half8 h; } u; u.s = s; return u.h;
}

// async global->LDS, 16B per lane; lds dest is wave-uniform base (HW adds lane*16)
__device__ __forceinline__ void load_lds_16(const void* g, void* l) {
  __builtin_amdgcn_global_load_lds(
      (const __attribute__((address_space(1))) uint_t*)g,
      (__attribute__((address_space(3))) uint_t*)l, 16, 0, 0);
}

// raw barriers (avoid __syncthreads' forced vmcnt drain where not needed)
__device__ __forceinline__ void barrier_vm0_lgkm0() {
  asm volatile("s_waitcnt vmcnt(0) lgkmcnt(0)\ns_barrier" ::: "memory");
}
__device__ __forceinline__ void barrier_lgkm0() {
  asm volatile("s_waitcnt lgkmcnt(0)\ns_barrier" ::: "memory");
}

// ---------------- wconv: Wq/Wk f32 -> f16 once (v13 proven) --------------------
__global__ __launch_bounds__(256) void wconv_kernel(
    const float* __restrict__ Wq, const float* __restrict__ Wk,
    _Float16* __restrict__ Whq, _Float16* __restrict__ Whk) {
  const int i = (blockIdx.x * 256 + threadIdx.x) * 8;
  half8 q = cvt8h(Wq + i);
  half8 k = cvt8h(Wk + i);
  *(half8*)(Whq + i) = q;
  *(half8*)(Whk + i) = k;
}

// ---------------- fused pre (v13 proven): proj (0..1023) + Vt^T (1024..2047) ----
__global__ __launch_bounds__(256, 2) void pre_kernel(
    const float* __restrict__ img, const float* __restrict__ text,
    const _Float16* __restrict__ Whq, const _Float16* __restrict__ Whk,
    _Float16* __restrict__ Qh, _Float16* __restrict__ Kh,
    ushort_t* __restrict__ Vt) {
  __shared__ float tile[64][65];
  const int bid = blockIdx.x;
  const int tid = threadIdx.x;
  if (bid < 1024) {
    const int bx = bid & 127;
    const int by = (bid >> 7) & 3;
    const int bz = bid >> 9;
    const int lane = tid & 63;
    const int wv = tid >> 6;
    const int l16 = lane & 15;
    const int quad = lane >> 4;
    const float* A = bz ? text : img;
    const _Float16* W = bz ? Whk : Whq;
    _Float16* C = bz ? Kh : Qh;
    const int row = bx * 64 + wv * 16 + l16;
    const int colbase = by * 64;

    float4v acc[4];
#pragma unroll
    for (int c = 0; c < 4; ++c) acc[c] = (float4v){0.f, 0.f, 0.f, 0.f};
#pragma unroll
    for (int f = 0; f < 8; ++f) {
      const int k0 = f * 32 + quad * 8;
      half8 af = cvt8h(A + (size_t)row * DIM + k0);
#pragma unroll
      for (int c = 0; c < 4; ++c) {
        half8 bfr = *(const half8*)(W + (size_t)(colbase + c * 16 + l16) * DIM + k0);
        acc[c] = MFMA_F16(af, bfr, acc[c]);
      }
    }
    const int rbase = bx * 64 + wv * 16 + quad * 4;
#pragma unroll
    for (int c = 0; c < 4; ++c)
#pragma unroll
      for (int r = 0; r < 4; ++r)
        C[(size_t)(rbase + r) * DIM + colbase + c * 16 + l16] = (_Float16)acc[c][r];
  } else {
    const int vb = bid - 1024;
    const int n0 = (vb & 127) * 64;
    const int c0 = (vb >> 7) * 64;
    const float* src = (c0 < 256) ? img : text;
    const int cc0 = (c0 < 256) ? c0 : (c0 - 256);
#pragma unroll
    for (int i = 0; i < 4; ++i) {
      const int r = i * 16 + (tid >> 4);
      const int c = (tid & 15) * 4;
      *(float4v*)&tile[r][c] = *(const float4v*)(src + (size_t)(n0 + r) * DIM + cc0 + c);
    }
    __syncthreads();
    const int c = tid >> 2;
    const int seg = tid & 3;
    ushort_t tmp[16];
#pragma unroll
    for (int t = 0; t < 16; ++t) tmp[t] = f2bf(tile[seg * 16 + t][c]);
    ushort_t* dst = Vt + (size_t)(c0 + c) * NQ + n0 + seg * 16;
    *(short8*)dst = *(short8*)&tmp[0];
    *(short8*)(dst + 8) = *(short8*)&tmp[8];
  }
}

// stage K tile (32 keys x 512B) into dbuf slot; XOR chunk swizzle on source
__device__ __forceinline__ void stage_K(const _Float16* __restrict__ Kh, int k0,
                                        ushort_t* dst, int tid, int wv) {
#pragma unroll
  for (int i = 0; i < 4; ++i) {
    const int chunk = i * 256 + tid;
    const int n = chunk >> 5;
    const int cs = (chunk & 31) ^ (n & 7);
    load_lds_16(Kh + (size_t)(k0 + n) * DIM + cs * 8,
                (char*)dst + (i * 256 + wv * 64) * 16);
  }
}
// stage V tile (512 vrows x 64B) into the single V buffer
__device__ __forceinline__ void stage_V(const ushort_t* __restrict__ Vt, int k0,
                                        ushort_t* dst, int tid, int wv) {
#pragma unroll
  for (int i = 0; i < 8; ++i) {
    const int chunk = i * 256 + tid;
    const int vrow = chunk >> 2;
    const int dc = (chunk & 3) ^ ((vrow >> 1) & 3);
    load_lds_16(Vt + (size_t)vrow * NQ + k0 + dc * 8,
                (char*)dst + (i * 256 + wv * 64) * 16);
  }
}

// PV step for NCT c-tiles starting at ctb (layouts identical to proven v13 code)
template <int NCT>
__device__ __forceinline__ void pv_step(float4v (&acc)[4][NCT],
                                        const ushort_t* __restrict__ Pprev,
                                        const ushort_t* __restrict__ ldsV,
                                        int ctb, int l16, int quad, int sw2) {
  short8 pa[4];
#pragma unroll
  for (int m = 0; m < 4; ++m)
    pa[m] = *(const short8*)(Pprev + (m * 16 + l16) * 32 + (quad ^ sw2) * 8);
  __builtin_amdgcn_s_setprio(1);
#pragma unroll
  for (int c = 0; c < NCT; ++c) {
    const int vcol = (ctb + c) * 16 + l16;
    short8 vb = *(const short8*)(ldsV + vcol * 32 + (quad ^ sw2) * 8);
#pragma unroll
    for (int m = 0; m < 4; ++m)
      acc[m][c] = MFMA_BF16(pa[m], vb, acc[m][c]);
  }
  __builtin_amdgcn_s_setprio(0);
}

// normalized epilogue store for NCT c-tiles starting at ctb
template <int NCT>
__device__ __forceinline__ void write_out(const float4v (&acc)[4][NCT],
                                          _Float16* __restrict__ pout,
                                          const float* __restrict__ ldsD,
                                          int ctb, int qtile, int l16, int quad) {
#pragma unroll
  for (int m = 0; m < 4; ++m) {
    float invd[4];
#pragma unroll
    for (int r = 0; r < 4; ++r) invd[r] = 1.0f / ldsD[m * 16 + quad * 4 + r];
    const int rowbase = qtile * 64 + m * 16 + quad * 4;
#pragma unroll
    for (int c = 0; c < NCT; ++c) {
      const int col = (ctb + c) * 16 + l16;
#pragma unroll
      for (int r = 0; r < 4; ++r)
        pout[(size_t)(rowbase + r) * DV + col] = (_Float16)(acc[m][c][r] * invd[r]);
    }
  }
}

// ---------------- fused attention v16: asymmetric wave roles --------------------
// attn is pinned at the LDS ds_read issue wall (~84 B/cy/CU measured = m134's
// b128 rate). Reads/block-tile = K 64 + V 32 + P 16 = 112 KB; K's 4x dup comes
// from every wave reading the full K tile for its 16 q-rows. v16 halves it:
// waves 0,1 ("S-waves") each own 32 q-rows (qf[2][8] = 64 VGPR) and compute ALL
// of S (K-read total 32 KB), plus a small PV slice (5 c-tiles, 80 acc);
// waves 2,3 ("PV-waves") do 11 c-tiles each (176 acc). MFMA cycles balanced
// (~260 vs ~220 per tile). Every fragment layout, the P format, swizzles and the
// barrier skeleton are byte-identical to v13, parameterized by (q-tiles, ct
// range); both branches execute identical barrier sequences. Reads drop to
// 80 KB/block-tile (-29%). LDS map unchanged: K dbuf @0,@8192; V @16384;
// P dbuf @32768,@34816. 72 KB -> 2 blocks/CU.
__global__ __launch_bounds__(256, 2) void attn_kernel(
    const _Float16* __restrict__ Qh, const _Float16* __restrict__ Kh,
    const ushort_t* __restrict__ Vt, _Float16* __restrict__ pacc,
    float* __restrict__ pdenom, int kps, int ks) {
  extern __shared__ __align__(16) ushort_t smem[];
  ushort_t* ldsV = smem + 16384;

  const int tid = threadIdx.x;
  const int lane = tid & 63;
  const int wv = tid >> 6;
  const int l16 = lane & 15;
  const int quad = lane >> 4;
  const int id = blockIdx.x;
  const int split = id & (ks - 1);
  const int qtile = id / ks;  // 0..127
  const int kbeg = split * kps;
  const int sw2 = (l16 >> 1) & 3;
  const int swk = l16 & 7;
  const int ntiles = kps >> 5;

  _Float16* pout = pacc + (size_t)split * ((size_t)NQ * DV);
  float* ldsD = (float*)smem;  // 64 floats (K area, dead at epilogue)

  // prologue: stage K(0) and V(0)
  stage_K(Kh, kbeg, smem, tid, wv);
  stage_V(Vt, kbeg, ldsV, tid, wv);

  if (wv < 2) {
    // ================= S-wave: q-tiles {2wv, 2wv+1}; PV c-tiles [5wv, 5wv+5) ===
    const int ctb = wv * 5;
    short8 qf[2][8];
#pragma unroll
    for (int j = 0; j < 2; ++j) {
      const _Float16* qptr =
          Qh + (size_t)(qtile * 64 + (2 * wv + j) * 16 + l16) * DIM;
#pragma unroll
      for (int f = 0; f < 8; ++f)
        qf[j][f] = *(const short8*)(qptr + f * 32 + quad * 8);
    }
    float4v acc[4][5];
#pragma unroll
    for (int m = 0; m < 4; ++m)
#pragma unroll
      for (int c = 0; c < 5; ++c) acc[m][c] = (float4v){0.f, 0.f, 0.f, 0.f};
    float dacc[2][4];
#pragma unroll
    for (int j = 0; j < 2; ++j)
#pragma unroll
      for (int r = 0; r < 4; ++r) dacc[j][r] = 0.f;

    for (int t = 0; t < ntiles; ++t) {
      const ushort_t* Kt = smem + (t & 1) * 8192;
      barrier_vm0_lgkm0();
      if (t + 1 < ntiles)
        stage_K(Kh, kbeg + (t + 1) * 32, smem + ((t + 1) & 1) * 8192, tid, wv);

      if (t > 0)
        pv_step<5>(acc, smem + 32768 + ((t - 1) & 1) * 2048, ldsV, ctb, l16,
                   quad, sw2);

      // S(t) for both q-tiles (16 q-rows each x 32 keys)
      float4v s[2][2];
      __builtin_amdgcn_s_setprio(1);
#pragma unroll
      for (int j = 0; j < 2; ++j) {
        s[j][0] = (float4v){0.f, 0.f, 0.f, 0.f};
        s[j][1] = (float4v){0.f, 0.f, 0.f, 0.f};
#pragma unroll
        for (int f = 0; f < 8; ++f) {
          const int cs = ((f * 4 + quad) ^ swk) * 8;
          short8 kb0 = *(const short8*)(Kt + l16 * DIM + cs);
          short8 kb1 = *(const short8*)(Kt + (l16 + 16) * DIM + cs);
          s[j][0] = MFMA_F16(as_h8(qf[j][f]), as_h8(kb0), s[j][0]);
          s[j][1] = MFMA_F16(as_h8(qf[j][f]), as_h8(kb1), s[j][1]);
        }
      }
      __builtin_amdgcn_s_setprio(0);

      barrier_lgkm0();
      if (t >= 1) stage_V(Vt, kbeg + t * 32, ldsV, tid, wv);

      // exp + P(t) write (v13 layout) + per-lane denom partials
      ushort_t* Pcur = smem + 32768 + (t & 1) * 2048;
#pragma unroll
      for (int j = 0; j < 2; ++j) {
#pragma unroll
        for (int r = 0; r < 4; ++r) {
          const ushort_t pb0 = f2bf(__expf(s[j][0][r]));  // key l16
          const ushort_t pb1 = f2bf(__expf(s[j][1][r]));  // key l16+16
          const int rb = (2 * wv + j) * 16 + quad * 4 + r;
          const int swp = (rb >> 1) & 3;
          Pcur[rb * 32 + ((l16 >> 3) ^ swp) * 8 + (l16 & 7)] = pb0;
          Pcur[rb * 32 + ((2 + (l16 >> 3)) ^ swp) * 8 + (l16 & 7)] = pb1;
          dacc[j][r] += bf2f(pb0) + bf2f(pb1);
        }
      }
    }

    // epilogue
    barrier_vm0_lgkm0();
    pv_step<5>(acc, smem + 32768 + ((ntiles - 1) & 1) * 2048, ldsV, ctb, l16,
               quad, sw2);
    // denominator butterfly over the 16 key-lanes
#pragma unroll
    for (int j = 0; j < 2; ++j)
#pragma unroll
      for (int r = 0; r < 4; ++r) {
        float ts = dacc[j][r];
        ts += __shfl_xor(ts, 1);
        ts += __shfl_xor(ts, 2);
        ts += __shfl_xor(ts, 4);
        ts += __shfl_xor(ts, 8);
        dacc[j][r] = ts;
      }
    barrier_lgkm0();
    if (l16 == 0) {
#pragma unroll
      for (int j = 0; j < 2; ++j)
#pragma unroll
        for (int r = 0; r < 4; ++r)
          ldsD[(2 * wv + j) * 16 + quad * 4 + r] = dacc[j][r];
    }
    barrier_lgkm0();
    write_out<5>(acc, pout, ldsD, ctb, qtile, l16, quad);
    if (l16 == 0) {
#pragma unroll
      for (int j = 0; j < 2; ++j)
#pragma unroll
        for (int r = 0; r < 4; ++r)
          pdenom[split * NQ + qtile * 64 + (2 * wv + j) * 16 + quad * 4 + r] =
              dacc[j][r];
    }
  } else {
    // ================= PV-wave: c-tiles [10 + 11*(wv-2), +11) =================
    const int ctb = 10 + (wv - 2) * 11;
    float4v acc[4][11];
#pragma unroll
    for (int m = 0; m < 4; ++m)
#pragma unroll
      for (int c = 0; c < 11; ++c) acc[m][c] = (float4v){0.f, 0.f, 0.f, 0.f};

    for (int t = 0; t < ntiles; ++t) {
      barrier_vm0_lgkm0();
      if (t + 1 < ntiles)
        stage_K(Kh, kbeg + (t + 1) * 32, smem + ((t + 1) & 1) * 8192, tid, wv);

      if (t > 0)
        pv_step<11>(acc, smem + 32768 + ((t - 1) & 1) * 2048, ldsV, ctb, l16,
                    quad, sw2);

      barrier_lgkm0();
      if (t >= 1) stage_V(Vt, kbeg + t * 32, ldsV, tid, wv);
    }

    // epilogue (barrier sequence matches the S-branch exactly)
    barrier_vm0_lgkm0();
    pv_step<11>(acc, smem + 32768 + ((ntiles - 1) & 1) * 2048, ldsV, ctb, l16,
                quad, sw2);
    barrier_lgkm0();
    barrier_lgkm0();
    write_out<11>(acc, pout, ldsD, ctb, qtile, l16, quad);
  }
}

// ---------------- combine: out = sum_i d_i*x_i / (16 * sum_i d_i) ----------------
__global__ __launch_bounds__(256) void combine_kernel(
    const _Float16* __restrict__ pacc, const float* __restrict__ pdenom,
    float* __restrict__ out, int ks) {
  const int idx = blockIdx.x * 256 + threadIdx.x;
  const int n = idx >> 6;
  const int c8 = (idx & 63) << 3;
  float s[8] = {0.f, 0.f, 0.f, 0.f, 0.f, 0.f, 0.f, 0.f};
  float dsum = 0.f;
  for (int sp = 0; sp < ks; ++sp) {
    const float d = pdenom[sp * NQ + n];
    half8 x = *(const half8*)(pacc + (size_t)sp * ((size_t)NQ * DV) + (size_t)n * DV + c8);
#pragma unroll
    for (int j = 0; j < 8; ++j) s[j] += d * (float)x[j];
    dsum += d;
  }
  const float scale = 1.0f / (16.0f * dsum);  // 1/sqrt(256) applied post-softmax
  float4v lo = (float4v){s[0], s[1], s[2], s[3]} * scale;
  float4v hi = (float4v){s[4], s[5], s[6], s[7]} * scale;
  float* dst = (c8 < 256) ? (out + (size_t)n * DIM + c8)
                          : (out + (size_t)NQ * DIM + (size_t)n * DIM + (c8 - 256));
  *(float4v*)dst = lo;
  *(float4v*)(dst + 4) = hi;
}

extern "C" void kernel_launch(void* const* d_in, const int* in_sizes, int n_in,
                              void* d_out, int out_size, void* d_ws, size_t ws_size,
                              hipStream_t stream) {
  const float* img = (const float*)d_in[0];
  const float* text = (const float*)d_in[1];
  const float* Wq = (const float*)d_in[2];
  const float* Wk = (const float*)d_in[3];
  float* out = (float*)d_out;
  char* ws = (char*)d_ws;

  _Float16* Qh = (_Float16*)ws;                        // 4 MiB
  _Float16* Kh = (_Float16*)(ws + ((size_t)4 << 20));  // 4 MiB
  ushort_t* Vt = (ushort_t*)(ws + ((size_t)8 << 20));  // 8 MiB
  const size_t accsz = (size_t)NQ * DV * sizeof(_Float16);  // 8 MiB per split
  const size_t base = (size_t)16 << 20;

  int ks = 4;
  if (ws_size < base + 4 * (accsz + NQ * sizeof(float))) ks = 2;
  _Float16* pacc = (_Float16*)(ws + base);
  float* pdenom = (float*)(ws + base + (size_t)ks * accsz);
  // Whq/Whk overlay the start of the pacc region (stream-ordered: wconv writes
  // -> pre reads -> attn overwrites with pacc).
  _Float16* Whq = (_Float16*)(ws + base);
  _Float16* Whk = Whq + DIM * DIM;

  hipLaunchKernelGGL(wconv_kernel, dim3(32), dim3(256), 0, stream,
                     Wq, Wk, Whq, Whk);
  hipLaunchKernelGGL(pre_kernel, dim3(2048), dim3(256), 0, stream,
                     img, text, Whq, Whk, Qh, Kh, Vt);
  hipLaunchKernelGGL(attn_kernel, dim3(128 * ks), dim3(256),
                     36864 * sizeof(ushort_t), stream,
                     Qh, Kh, Vt, pacc, pdenom, NQ / ks, ks);
  hipLaunchKernelGGL(combine_kernel, dim3((NQ * DV / 8) / 256), dim3(256), 0, stream,
                     pacc, pdenom, out, ks);
}

// Round 14
// 231.562 us; speedup vs baseline: 1.3189x; 1.3189x over previous
//
#include <hip/hip_runtime.h>

typedef unsigned short ushort_t;
typedef unsigned int uint_t;
typedef __attribute__((ext_vector_type(8))) short short8;
typedef __attribute__((ext_vector_type(8))) _Float16 half8;
typedef __attribute__((ext_vector_type(4))) _Float16 half4;
typedef __attribute__((ext_vector_type(4))) float float4v;

#define MFMA_BF16(a, b, c) __builtin_amdgcn_mfma_f32_16x16x32_bf16((a), (b), (c), 0, 0, 0)
#define MFMA_F16(a, b, c) __builtin_amdgcn_mfma_f32_16x16x32_f16((a), (b), (c), 0, 0, 0)

#define NQ 8192
#define DIM 256
#define DV 512

// round-to-nearest-even f32 -> bf16 (raw bits)
__device__ __forceinline__ ushort_t f2bf(float x) {
  union { float f; uint_t u; } v; v.f = x;
  return (ushort_t)((v.u + 0x7fffu + ((v.u >> 16) & 1u)) >> 16);
}
__device__ __forceinline__ float bf2f(ushort_t b) {
  union { uint_t u; float f; } v; v.u = ((uint_t)b) << 16;
  return v.f;
}

__device__ __forceinline__ half8 cvt8h(const float* p) {
  float4v a = *(const float4v*)p;
  float4v b = *(const float4v*)(p + 4);
  half8 r;
  r[0] = (_Float16)a[0]; r[1] = (_Float16)a[1];
  r[2] = (_Float16)a[2]; r[3] = (_Float16)a[3];
  r[4] = (_Float16)b[0]; r[5] = (_Float16)b[1];
  r[6] = (_Float16)b[2]; r[7] = (_Float16)b[3];
  return r;
}

__device__ __forceinline__ half8 as_h8(short8 s) {
  union { short8 s; half8 h; } u; u.s = s; return u.h;
}

// async global->LDS, 16B per lane; lds dest is wave-uniform base (HW adds lane*16)
__device__ __forceinline__ void load_lds_16(const void* g, void* l) {
  __builtin_amdgcn_global_load_lds(
      (const __attribute__((address_space(1))) uint_t*)g,
      (__attribute__((address_space(3))) uint_t*)l, 16, 0, 0);
}

// raw barriers (avoid __syncthreads' forced vmcnt drain where not needed)
__device__ __forceinline__ void barrier_vm0_lgkm0() {
  asm volatile("s_waitcnt vmcnt(0) lgkmcnt(0)\ns_barrier" ::: "memory");
}
__device__ __forceinline__ void barrier_lgkm0() {
  asm volatile("s_waitcnt lgkmcnt(0)\ns_barrier" ::: "memory");
}

// ---------------- wconv: Wq/Wk f32 -> f16, ONCE (proven +5us vs per-block) ------
__global__ __launch_bounds__(256) void wconv_kernel(
    const float* __restrict__ Wq, const float* __restrict__ Wk,
    _Float16* __restrict__ Whq, _Float16* __restrict__ Whk) {
  const int i = (blockIdx.x * 256 + threadIdx.x) * 8;
  half8 q = cvt8h(Wq + i);
  half8 k = cvt8h(Wk + i);
  *(half8*)(Whq + i) = q;
  *(half8*)(Whk + i) = k;
}

// ---------------- fused pre (proven): proj (0..1023) + Vt^T (1024..2047) --------
__global__ __launch_bounds__(256, 2) void pre_kernel(
    const float* __restrict__ img, const float* __restrict__ text,
    const _Float16* __restrict__ Whq, const _Float16* __restrict__ Whk,
    _Float16* __restrict__ Qh, _Float16* __restrict__ Kh,
    ushort_t* __restrict__ Vt) {
  __shared__ float tile[64][65];
  const int bid = blockIdx.x;
  const int tid = threadIdx.x;
  if (bid < 1024) {
    // ---- projection: 64x64 tile of img@Wq^T (z=0) or text@Wk^T (z=1) ----
    const int bx = bid & 127;
    const int by = (bid >> 7) & 3;
    const int bz = bid >> 9;
    const int lane = tid & 63;
    const int wv = tid >> 6;
    const int l16 = lane & 15;
    const int quad = lane >> 4;
    const float* A = bz ? text : img;
    const _Float16* W = bz ? Whk : Whq;
    _Float16* C = bz ? Kh : Qh;
    const int row = bx * 64 + wv * 16 + l16;
    const int colbase = by * 64;

    float4v acc[4];
#pragma unroll
    for (int c = 0; c < 4; ++c) acc[c] = (float4v){0.f, 0.f, 0.f, 0.f};
#pragma unroll
    for (int f = 0; f < 8; ++f) {
      const int k0 = f * 32 + quad * 8;
      half8 af = cvt8h(A + (size_t)row * DIM + k0);
#pragma unroll
      for (int c = 0; c < 4; ++c) {
        half8 bfr = *(const half8*)(W + (size_t)(colbase + c * 16 + l16) * DIM + k0);
        acc[c] = MFMA_F16(af, bfr, acc[c]);
      }
    }
    const int rbase = bx * 64 + wv * 16 + quad * 4;
#pragma unroll
    for (int c = 0; c < 4; ++c)
#pragma unroll
      for (int r = 0; r < 4; ++r)
        C[(size_t)(rbase + r) * DIM + colbase + c * 16 + l16] = (_Float16)acc[c][r];
  } else {
    // ---- Vt = bf16([img | text]^T), 64x64 transpose tiles ----
    const int vb = bid - 1024;
    const int n0 = (vb & 127) * 64;
    const int c0 = (vb >> 7) * 64;
    const float* src = (c0 < 256) ? img : text;
    const int cc0 = (c0 < 256) ? c0 : (c0 - 256);
#pragma unroll
    for (int i = 0; i < 4; ++i) {
      const int r = i * 16 + (tid >> 4);
      const int c = (tid & 15) * 4;
      *(float4v*)&tile[r][c] = *(const float4v*)(src + (size_t)(n0 + r) * DIM + cc0 + c);
    }
    __syncthreads();
    const int c = tid >> 2;
    const int seg = tid & 3;
    ushort_t tmp[16];
#pragma unroll
    for (int t = 0; t < 16; ++t) tmp[t] = f2bf(tile[seg * 16 + t][c]);
    ushort_t* dst = Vt + (size_t)(c0 + c) * NQ + n0 + seg * 16;
    *(short8*)dst = *(short8*)&tmp[0];
    *(short8*)(dst + 8) = *(short8*)&tmp[8];
  }
}

// stage K tile (32 keys x 512B) into dbuf slot; XOR chunk swizzle on source
__device__ __forceinline__ void stage_K(const _Float16* __restrict__ Kh, int k0,
                                        ushort_t* dst, int tid, int wv) {
#pragma unroll
  for (int i = 0; i < 4; ++i) {
    const int chunk = i * 256 + tid;
    const int n = chunk >> 5;
    const int cs = (chunk & 31) ^ (n & 7);
    load_lds_16(Kh + (size_t)(k0 + n) * DIM + cs * 8,
                (char*)dst + (i * 256 + wv * 64) * 16);
  }
}
// stage V tile (512 vrows x 64B) into the single V buffer
__device__ __forceinline__ void stage_V(const ushort_t* __restrict__ Vt, int k0,
                                        ushort_t* dst, int tid, int wv) {
#pragma unroll
  for (int i = 0; i < 8; ++i) {
    const int chunk = i * 256 + tid;
    const int vrow = chunk >> 2;
    const int dc = (chunk & 3) ^ ((vrow >> 1) & 3);
    load_lds_16(Vt + (size_t)vrow * NQ + k0 + dc * 8,
                (char*)dst + (i * 256 + wv * 64) * 16);
  }
}

// ---------------- fused attention v13 (proven 142.5us): v9 + setprio -----------
// Pinned by three walls (rounds 4-13 evidence): LDS ds_read issue ~84 B/cy/CU
// (= m134 b128 ceiling); 124 VGPR + 128 acc = 252/256 regs (no restructure
// headroom -- v16's asymmetric roles spilled, v4/v5's global-V exposed L2
// latency); 2 blocks/CU barrier-synced. LDS: K dbuf @0,@8192; V @16384;
// P dbuf @32768,@34816. 72KB.
__global__ __launch_bounds__(256, 2) void attn_kernel(
    const _Float16* __restrict__ Qh, const _Float16* __restrict__ Kh,
    const ushort_t* __restrict__ Vt, _Float16* __restrict__ pacc,
    float* __restrict__ pdenom, int kps, int ks) {
  extern __shared__ __align__(16) ushort_t smem[];
  ushort_t* ldsV = smem + 16384;

  const int tid = threadIdx.x;
  const int lane = tid & 63;
  const int wv = tid >> 6;
  const int l16 = lane & 15;
  const int quad = lane >> 4;
  const int id = blockIdx.x;
  const int split = id & (ks - 1);
  const int qtile = id / ks;  // 0..127
  const int kbeg = split * kps;
  const int sw2 = (l16 >> 1) & 3;
  const int swk = l16 & 7;

  // Q fragments for this wave's 16 S-rows: A-layout m=l16, k=quad*8+j
  short8 qf[8];
  {
    const _Float16* qptr = Qh + (size_t)(qtile * 64 + wv * 16 + l16) * DIM;
#pragma unroll
    for (int f = 0; f < 8; ++f)
      qf[f] = *(const short8*)(qptr + f * 32 + quad * 8);
  }

  float4v acc[4][8];
#pragma unroll
  for (int m = 0; m < 4; ++m)
#pragma unroll
    for (int c = 0; c < 8; ++c) acc[m][c] = (float4v){0.f, 0.f, 0.f, 0.f};
  float dacc[4] = {0.f, 0.f, 0.f, 0.f};

  const int ntiles = kps >> 5;

  // prologue: stage K(0) and V(0)
  stage_K(Kh, kbeg, smem, tid, wv);
  stage_V(Vt, kbeg, ldsV, tid, wv);

  for (int t = 0; t < ntiles; ++t) {
    const ushort_t* Kt = smem + (t & 1) * 8192;
    // B1: K(t) + V(t-1 or prologue V(0)) staged (vm0); P(t-1) writes visible (lgkm0)
    barrier_vm0_lgkm0();
    // prefetch K(t+1) into the K slot freed by S(t-1)
    if (t + 1 < ntiles)
      stage_K(Kh, kbeg + (t + 1) * 32, smem + ((t + 1) & 1) * 8192, tid, wv);

    // PV(t-1): wave owns vcols [wv*128, wv*128+128) for all 64 q-rows
    if (t > 0) {
      const ushort_t* Pprev = smem + 32768 + ((t - 1) & 1) * 2048;
      short8 pa[4];
#pragma unroll
      for (int m = 0; m < 4; ++m)
        pa[m] = *(const short8*)(Pprev + (m * 16 + l16) * 32 + (quad ^ sw2) * 8);
      __builtin_amdgcn_s_setprio(1);
#pragma unroll
      for (int c = 0; c < 8; ++c) {
        const int vcol = (wv * 8 + c) * 16 + l16;
        short8 vb = *(const short8*)(ldsV + vcol * 32 + (quad ^ sw2) * 8);
#pragma unroll
        for (int m = 0; m < 4; ++m)
          acc[m][c] = MFMA_BF16(pa[m], vb, acc[m][c]);
      }
      __builtin_amdgcn_s_setprio(0);
    }

    // S(t) = Q K^T (this wave's 16 q-rows x 32 keys)
    float4v s0 = (float4v){0.f, 0.f, 0.f, 0.f};
    float4v s1 = (float4v){0.f, 0.f, 0.f, 0.f};
    __builtin_amdgcn_s_setprio(1);
#pragma unroll
    for (int f = 0; f < 8; ++f) {
      const int cs = ((f * 4 + quad) ^ swk) * 8;
      short8 kb0 = *(const short8*)(Kt + l16 * DIM + cs);
      short8 kb1 = *(const short8*)(Kt + (l16 + 16) * DIM + cs);
      s0 = MFMA_F16(as_h8(qf[f]), as_h8(kb0), s0);
      s1 = MFMA_F16(as_h8(qf[f]), as_h8(kb1), s1);
    }
    __builtin_amdgcn_s_setprio(0);

    // B2: all PV(t-1)/S(t) LDS reads retired -> V buffer free to restage
    barrier_lgkm0();
    // stage V(t): PV(t) reads it at iter t+1 (or epilogue)
    if (t >= 1) stage_V(Vt, kbeg + t * 32, ldsV, tid, wv);

    // exp + write P(t) + per-lane denom partials (reduction deferred to epilogue)
    ushort_t* Pcur = smem + 32768 + (t & 1) * 2048;
    ushort_t pb0[4], pb1[4];
#pragma unroll
    for (int r = 0; r < 4; ++r) {
      pb0[r] = f2bf(__expf(s0[r]));
      pb1[r] = f2bf(__expf(s1[r]));
    }
#pragma unroll
    for (int r = 0; r < 4; ++r) {
      const int rb = wv * 16 + quad * 4 + r;
      const int swp = (rb >> 1) & 3;
      Pcur[rb * 32 + ((l16 >> 3) ^ swp) * 8 + (l16 & 7)] = pb0[r];
      Pcur[rb * 32 + ((2 + (l16 >> 3)) ^ swp) * 8 + (l16 & 7)] = pb1[r];
      dacc[r] += bf2f(pb0[r]) + bf2f(pb1[r]);
    }
  }

  // epilogue: final PV(ntiles-1)
  barrier_vm0_lgkm0();
  {
    const ushort_t* Pprev = smem + 32768 + ((ntiles - 1) & 1) * 2048;
    short8 pa[4];
#pragma unroll
    for (int m = 0; m < 4; ++m)
      pa[m] = *(const short8*)(Pprev + (m * 16 + l16) * 32 + (quad ^ sw2) * 8);
#pragma unroll
    for (int c = 0; c < 8; ++c) {
      const int vcol = (wv * 8 + c) * 16 + l16;
      short8 vb = *(const short8*)(ldsV + vcol * 32 + (quad ^ sw2) * 8);
#pragma unroll
      for (int m = 0; m < 4; ++m)
        acc[m][c] = MFMA_BF16(pa[m], vb, acc[m][c]);
    }
  }

  // deferred denominator reduction: one butterfly over the 16 key-lanes
#pragma unroll
  for (int r = 0; r < 4; ++r) {
    float ts = dacc[r];
    ts += __shfl_xor(ts, 1);
    ts += __shfl_xor(ts, 2);
    ts += __shfl_xor(ts, 4);
    ts += __shfl_xor(ts, 8);
    dacc[r] = ts;
  }

  // exchange denoms via LDS (K area, dead now), store normalized fp16 partials
  barrier_lgkm0();
  float* ldsD = (float*)smem;  // 64 floats
  if (l16 == 0) {
#pragma unroll
    for (int r = 0; r < 4; ++r)
      ldsD[wv * 16 + quad * 4 + r] = dacc[r];
  }
  barrier_lgkm0();

  _Float16* pout = pacc + (size_t)split * ((size_t)NQ * DV);
#pragma unroll
  for (int m = 0; m < 4; ++m) {
    float invd[4];
#pragma unroll
    for (int r = 0; r < 4; ++r) invd[r] = 1.0f / ldsD[m * 16 + quad * 4 + r];
    const int rowbase = qtile * 64 + m * 16 + quad * 4;
#pragma unroll
    for (int c = 0; c < 8; ++c) {
      const int col = (wv * 8 + c) * 16 + l16;
#pragma unroll
      for (int r = 0; r < 4; ++r)
        pout[(size_t)(rowbase + r) * DV + col] = (_Float16)(acc[m][c][r] * invd[r]);
    }
  }
  if (l16 == 0) {
    const int rowbase = qtile * 64 + wv * 16 + quad * 4;
#pragma unroll
    for (int r = 0; r < 4; ++r)
      pdenom[split * NQ + rowbase + r] = dacc[r];
  }
}

// ---------------- combine: out = sum_i d_i*x_i / (16 * sum_i d_i) ----------------
// half8 (16B/lane) loads, 2x float4v (32B/lane) stores; 8 cols per thread.
__global__ __launch_bounds__(256) void combine_kernel(
    const _Float16* __restrict__ pacc, const float* __restrict__ pdenom,
    float* __restrict__ out, int ks) {
  const int idx = blockIdx.x * 256 + threadIdx.x;
  const int n = idx >> 6;
  const int c8 = (idx & 63) << 3;
  float s[8] = {0.f, 0.f, 0.f, 0.f, 0.f, 0.f, 0.f, 0.f};
  float dsum = 0.f;
  for (int sp = 0; sp < ks; ++sp) {
    const float d = pdenom[sp * NQ + n];
    half8 x = *(const half8*)(pacc + (size_t)sp * ((size_t)NQ * DV) + (size_t)n * DV + c8);
#pragma unroll
    for (int j = 0; j < 8; ++j) s[j] += d * (float)x[j];
    dsum += d;
  }
  const float scale = 1.0f / (16.0f * dsum);  // 1/sqrt(256) applied post-softmax
  float4v lo = (float4v){s[0], s[1], s[2], s[3]} * scale;
  float4v hi = (float4v){s[4], s[5], s[6], s[7]} * scale;
  float* dst = (c8 < 256) ? (out + (size_t)n * DIM + c8)
                          : (out + (size_t)NQ * DIM + (size_t)n * DIM + (c8 - 256));
  *(float4v*)dst = lo;
  *(float4v*)(dst + 4) = hi;
}

extern "C" void kernel_launch(void* const* d_in, const int* in_sizes, int n_in,
                              void* d_out, int out_size, void* d_ws, size_t ws_size,
                              hipStream_t stream) {
  const float* img = (const float*)d_in[0];
  const float* text = (const float*)d_in[1];
  const float* Wq = (const float*)d_in[2];
  const float* Wk = (const float*)d_in[3];
  float* out = (float*)d_out;
  char* ws = (char*)d_ws;

  _Float16* Qh = (_Float16*)ws;                        // 4 MiB
  _Float16* Kh = (_Float16*)(ws + ((size_t)4 << 20));  // 4 MiB
  ushort_t* Vt = (ushort_t*)(ws + ((size_t)8 << 20));  // 8 MiB
  const size_t accsz = (size_t)NQ * DV * sizeof(_Float16);  // 8 MiB per split
  const size_t base = (size_t)16 << 20;

  int ks = 4;
  if (ws_size < base + 4 * (accsz + NQ * sizeof(float))) ks = 2;
  _Float16* pacc = (_Float16*)(ws + base);
  float* pdenom = (float*)(ws + base + (size_t)ks * accsz);
  // Whq/Whk overlay the start of the pacc region (stream-ordered: wconv writes
  // -> pre reads -> attn overwrites with pacc).
  _Float16* Whq = (_Float16*)(ws + base);
  _Float16* Whk = Whq + DIM * DIM;

  hipLaunchKernelGGL(wconv_kernel, dim3(32), dim3(256), 0, stream,
                     Wq, Wk, Whq, Whk);
  hipLaunchKernelGGL(pre_kernel, dim3(2048), dim3(256), 0, stream,
                     img, text, Whq, Whk, Qh, Kh, Vt);
  hipLaunchKernelGGL(attn_kernel, dim3(128 * ks), dim3(256),
                     36864 * sizeof(ushort_t), stream,
                     Qh, Kh, Vt, pacc, pdenom, NQ / ks, ks);
  hipLaunchKernelGGL(combine_kernel, dim3((NQ * DV / 8) / 256), dim3(256), 0, stream,
                     pacc, pdenom, out, ks);
}